// Round 1
// baseline (92.792 us; speedup 1.0000x reference)
//
#include <hip/hip_runtime.h>

#define BATCH 32
#define SEQ   4096
#define HID   512

// v[b,h] = sum_o hidden[b,o] * W[o,h]   (b_attn cancels in softmax)
__global__ void __launch_bounds__(256) compute_v_kernel(
        const float* __restrict__ hidden,
        const float* __restrict__ W,
        float* __restrict__ v) {
    int b = blockIdx.x;
    __shared__ float sh[HID];
    for (int i = threadIdx.x; i < HID; i += 256) sh[i] = hidden[b * HID + i];
    __syncthreads();
    for (int h = threadIdx.x; h < HID; h += 256) {
        float acc = 0.f;
        #pragma unroll 8
        for (int o = 0; o < HID; ++o)
            acc = fmaf(sh[o], W[o * HID + h], acc);   // coalesced across threads
        v[b * HID + h] = acc;
    }
}

// scores[b,s] = dot(enc[b,s,:], v[b,:]) — one wave per row, grid-stride
__global__ void __launch_bounds__(256) scores_kernel(
        const float* __restrict__ enc,
        const float* __restrict__ v,
        float* __restrict__ scores) {
    const long long total_rows = (long long)BATCH * SEQ;
    int wave = threadIdx.x >> 6;
    int lane = threadIdx.x & 63;
    long long row0 = (long long)blockIdx.x * 4 + wave;
    long long row_stride = (long long)gridDim.x * 4;

    for (long long row = row0; row < total_rows; row += row_stride) {
        int b = (int)(row >> 12);                     // row / 4096
        const float4* e4 = (const float4*)(enc + row * HID);
        const float4* v4 = (const float4*)(v + (long long)b * HID);
        float4 e0 = e4[lane];        // h = lane*4 .. lane*4+3      (coalesced)
        float4 e1 = e4[lane + 64];   // h = 256 + lane*4 ..         (coalesced)
        float4 v0 = v4[lane];
        float4 v1 = v4[lane + 64];
        float acc = e0.x * v0.x + e0.y * v0.y + e0.z * v0.z + e0.w * v0.w
                  + e1.x * v1.x + e1.y * v1.y + e1.z * v1.z + e1.w * v1.w;
        #pragma unroll
        for (int m = 32; m > 0; m >>= 1) acc += __shfl_xor(acc, m, 64);
        if (lane == 0) scores[row] = acc;
    }
}

// in-place softmax over the 4096 scores of each batch row (one block per b)
__global__ void __launch_bounds__(256) softmax_kernel(float* __restrict__ data) {
    int b = blockIdx.x;
    float* row = data + (long long)b * SEQ;
    int wave = threadIdx.x >> 6, lane = threadIdx.x & 63;

    float vals[16];
    float m = -1e30f;
    #pragma unroll
    for (int i = 0; i < 16; ++i) {
        vals[i] = row[threadIdx.x + i * 256];
        m = fmaxf(m, vals[i]);
    }
    #pragma unroll
    for (int s = 32; s > 0; s >>= 1) m = fmaxf(m, __shfl_xor(m, s, 64));
    __shared__ float red_max[4];
    if (lane == 0) red_max[wave] = m;
    __syncthreads();
    m = fmaxf(fmaxf(red_max[0], red_max[1]), fmaxf(red_max[2], red_max[3]));

    float sum = 0.f;
    #pragma unroll
    for (int i = 0; i < 16; ++i) {
        vals[i] = __expf(vals[i] - m);
        sum += vals[i];
    }
    #pragma unroll
    for (int s = 32; s > 0; s >>= 1) sum += __shfl_xor(sum, s, 64);
    __shared__ float red_sum[4];
    if (lane == 0) red_sum[wave] = sum;
    __syncthreads();
    sum = red_sum[0] + red_sum[1] + red_sum[2] + red_sum[3];

    float inv = 1.f / sum;
    #pragma unroll
    for (int i = 0; i < 16; ++i)
        row[threadIdx.x + i * 256] = vals[i] * inv;
}

extern "C" void kernel_launch(void* const* d_in, const int* in_sizes, int n_in,
                              void* d_out, int out_size, void* d_ws, size_t ws_size,
                              hipStream_t stream) {
    const float* hidden = (const float*)d_in[0];   // [1,B,H]
    const float* enc    = (const float*)d_in[1];   // [B,S,H]
    const float* W      = (const float*)d_in[2];   // [H,H] row-major [o][h]
    // d_in[3] = b_attn: constant per-row shift inside softmax -> cancels; unused.
    float* out = (float*)d_out;                    // [B,1,S] == B*S floats
    float* v   = (float*)d_ws;                     // B*H floats = 64 KB scratch

    compute_v_kernel<<<BATCH, 256, 0, stream>>>(hidden, W, v);
    // scores written straight into d_out (exactly B*S floats), softmax in-place
    scores_kernel<<<2048, 256, 0, stream>>>(enc, v, out);
    softmax_kernel<<<BATCH, 256, 0, stream>>>(out);
}

// Round 2
// 54.212 us; speedup vs baseline: 1.7116x; 1.7116x over previous
//
#include <hip/hip_runtime.h>

#define BATCH 32
#define SEQ   4096
#define HID   512

// v[b,h] = sum_o hidden[b,o] * W[o,h]   (b_attn cancels in softmax)
// grid (32, 8): block = (batch b, 64-wide h-chunk); o split across 4 wave-groups
__global__ void __launch_bounds__(256) compute_v_kernel(
        const float* __restrict__ hidden,
        const float* __restrict__ W,
        float* __restrict__ v) {
    int b  = blockIdx.x;
    int h  = blockIdx.y * 64 + (threadIdx.x & 63);
    int oq = threadIdx.x >> 6;                     // 0..3, o-quarter
    __shared__ float sh[HID];
    for (int i = threadIdx.x; i < HID; i += 256) sh[i] = hidden[b * HID + i];
    __syncthreads();
    float acc = 0.f;
    int o0 = oq * 128;
    #pragma unroll 8
    for (int o = o0; o < o0 + 128; ++o)
        acc = fmaf(sh[o], W[o * HID + h], acc);    // 64 consecutive floats/quarter-wave
    __shared__ float red[4][64];
    red[oq][threadIdx.x & 63] = acc;
    __syncthreads();
    if (threadIdx.x < 64)
        v[b * HID + h] = red[0][threadIdx.x] + red[1][threadIdx.x]
                       + red[2][threadIdx.x] + red[3][threadIdx.x];
}

// scores[b,s] = dot(enc[b,s,:], v[b,:])
// wave = 16 consecutive rows of ONE batch -> v hoisted to registers;
// 4-row unroll (8 KB in flight); packed dual-row shuffle reduce.
__global__ void __launch_bounds__(256) scores_kernel(
        const float* __restrict__ enc,
        const float* __restrict__ v,
        float* __restrict__ scores) {
    int wid  = blockIdx.x * 4 + (threadIdx.x >> 6);   // 0..8191
    int lane = threadIdx.x & 63;
    int b    = wid >> 8;                              // 256 waves per batch
    long long row0 = (long long)wid * 16;

    const float4* v4 = (const float4*)(v + (long long)b * HID);
    float4 v0 = v4[lane];          // h = 4*lane..     (L1/L2 hit, loaded once)
    float4 v1 = v4[lane + 64];

    for (int r = 0; r < 16; r += 4) {
        const float4* e0 = (const float4*)(enc + (row0 + r)     * HID);
        const float4* e1 = (const float4*)(enc + (row0 + r + 1) * HID);
        const float4* e2 = (const float4*)(enc + (row0 + r + 2) * HID);
        const float4* e3 = (const float4*)(enc + (row0 + r + 3) * HID);
        float4 a0 = e0[lane], a1 = e0[lane + 64];     // 8 coalesced float4 loads
        float4 b0 = e1[lane], b1 = e1[lane + 64];     // all issued before any use
        float4 c0 = e2[lane], c1 = e2[lane + 64];
        float4 d0 = e3[lane], d1 = e3[lane + 64];

        float accA = a0.x*v0.x + a0.y*v0.y + a0.z*v0.z + a0.w*v0.w
                   + a1.x*v1.x + a1.y*v1.y + a1.z*v1.z + a1.w*v1.w;
        float accB = b0.x*v0.x + b0.y*v0.y + b0.z*v0.z + b0.w*v0.w
                   + b1.x*v1.x + b1.y*v1.y + b1.z*v1.z + b1.w*v1.w;
        float accC = c0.x*v0.x + c0.y*v0.y + c0.z*v0.z + c0.w*v0.w
                   + c1.x*v1.x + c1.y*v1.y + c1.z*v1.z + c1.w*v1.w;
        float accD = d0.x*v0.x + d0.y*v0.y + d0.z*v0.z + d0.w*v0.w
                   + d1.x*v1.x + d1.y*v1.y + d1.z*v1.z + d1.w*v1.w;

        // pack rows (A,B) into (lower,upper) 32-lane halves: one xor-32 swap,
        // then a single 5-level fold reduces both rows at once. Same for (C,D).
        float zab = (lane < 32) ? accA : accB;
        zab += __shfl_xor((lane < 32) ? accB : accA, 32, 64);
        float zcd = (lane < 32) ? accC : accD;
        zcd += __shfl_xor((lane < 32) ? accD : accC, 32, 64);
        #pragma unroll
        for (int m = 16; m > 0; m >>= 1) {
            zab += __shfl_xor(zab, m, 64);
            zcd += __shfl_xor(zcd, m, 64);
        }
        if (lane == 0)  { scores[row0 + r]     = zab; scores[row0 + r + 2] = zcd; }
        if (lane == 32) { scores[row0 + r + 1] = zab; scores[row0 + r + 3] = zcd; }
    }
}

// in-place softmax over 4096 scores per batch row; 1024 threads, float4 I/O
__global__ void __launch_bounds__(1024) softmax_kernel(float* __restrict__ data) {
    int b = blockIdx.x;
    float4* row4 = (float4*)(data + (long long)b * SEQ);
    int t = threadIdx.x, wave = t >> 6, lane = t & 63;

    float4 vv = row4[t];                               // coalesced, 16 KB/block
    float m = fmaxf(fmaxf(vv.x, vv.y), fmaxf(vv.z, vv.w));
    #pragma unroll
    for (int s = 32; s > 0; s >>= 1) m = fmaxf(m, __shfl_xor(m, s, 64));
    __shared__ float red_max[16];
    if (lane == 0) red_max[wave] = m;
    __syncthreads();
    m = red_max[0];
    #pragma unroll
    for (int i = 1; i < 16; ++i) m = fmaxf(m, red_max[i]);

    vv.x = __expf(vv.x - m); vv.y = __expf(vv.y - m);
    vv.z = __expf(vv.z - m); vv.w = __expf(vv.w - m);
    float sum = vv.x + vv.y + vv.z + vv.w;
    #pragma unroll
    for (int s = 32; s > 0; s >>= 1) sum += __shfl_xor(sum, s, 64);
    __shared__ float red_sum[16];
    if (lane == 0) red_sum[wave] = sum;
    __syncthreads();
    sum = 0.f;
    #pragma unroll
    for (int i = 0; i < 16; ++i) sum += red_sum[i];

    float inv = 1.f / sum;
    vv.x *= inv; vv.y *= inv; vv.z *= inv; vv.w *= inv;
    row4[t] = vv;
}

extern "C" void kernel_launch(void* const* d_in, const int* in_sizes, int n_in,
                              void* d_out, int out_size, void* d_ws, size_t ws_size,
                              hipStream_t stream) {
    const float* hidden = (const float*)d_in[0];   // [1,B,H]
    const float* enc    = (const float*)d_in[1];   // [B,S,H]
    const float* W      = (const float*)d_in[2];   // [H,H] row-major [o][h]
    // d_in[3] = b_attn: constant per-row shift inside softmax -> cancels; unused.
    float* out = (float*)d_out;                    // [B,1,S] == B*S floats
    float* v   = (float*)d_ws;                     // B*H floats = 64 KB scratch

    compute_v_kernel<<<dim3(BATCH, HID / 64), 256, 0, stream>>>(hidden, W, v);
    scores_kernel<<<(BATCH * SEQ) / (16 * 4), 256, 0, stream>>>(enc, v, out);
    softmax_kernel<<<BATCH, 1024, 0, stream>>>(out);
}